// Round 1
// baseline (5205.319 us; speedup 1.0000x reference)
//
#include <hip/hip_runtime.h>
#include <hip/hip_bf16.h>

#define LFULL 8192
#define HDIM 1024

// ---------------------------------------------------------------------------
// Kernel 1: multi-scale kernel synthesis + L2 normalization.
// One block per h. parts: i=0..7, scale s=2^max(0,i-1), lengths 64,64,128,...,4096
// offsets 0,64,128,256,...,4096. val = interp(kernels[i][0][h], t) * mult^(7-i)
// ---------------------------------------------------------------------------
__global__ __launch_bounds__(256) void k_synth_kernel(
    const float* __restrict__ kern, float* __restrict__ kout) {
  const int h = blockIdx.x;
  const int tid = threadIdx.x;
  __shared__ float Kw[8][64];
  __shared__ __align__(16) float kv[LFULL];
  __shared__ float red[8];
  for (int idx = tid; idx < 8 * 64; idx += 256) {
    int i = idx >> 6, j = idx & 63;
    Kw[i][j] = kern[(i * HDIM + h) * 64 + j];
  }
  __syncthreads();
  const float mult = (float)(1.0 + 3.0 * (double)h / 1023.0);
  float pw[8];
  pw[7] = 1.0f;
#pragma unroll
  for (int i = 6; i >= 0; --i) pw[i] = pw[i + 1] * mult;
  float ss = 0.0f;
  for (int m = tid; m < LFULL; m += 256) {
    const int i = (m < 64) ? 0 : (32 - __clz(m >> 6));
    const int slog = (i == 0) ? 0 : (i - 1);
    const float inv_s = 1.0f / (float)(1 << slog);
    const int off = (i == 0) ? 0 : (64 << (i - 1));
    const int t = m - off;
    const float pos = ((float)t + 0.5f) * inv_s - 0.5f;
    const float lof = floorf(pos);
    const float w = pos - lof;
    int lo = (int)lof;
    int hi = lo + 1;
    lo = min(63, max(0, lo));
    hi = min(63, max(0, hi));
    const float val = (Kw[i][lo] * (1.0f - w) + Kw[i][hi] * w) * pw[i];
    kv[m] = val;
    ss += val * val;
  }
#pragma unroll
  for (int o = 32; o > 0; o >>= 1) ss += __shfl_xor(ss, o, 64);
  if ((tid & 63) == 0) red[tid >> 6] = ss;
  __syncthreads();
  if (tid == 0) red[0] = sqrtf(red[0] + red[1] + red[2] + red[3]);
  __syncthreads();
  const float inv_norm = 1.0f / red[0];
  float* krow = kout + (size_t)h * LFULL;
  for (int m = tid; m < LFULL; m += 256) krow[m] = kv[m] * inv_norm;
}

// ---------------------------------------------------------------------------
// Kernel 2: causal conv + skip + exact GELU -> bf16 g.
// One block per (b,h). u row + k row resident in LDS (64 KB).
// Each thread: 4 chunks of 8 consecutive outputs; sliding 16-float window,
// fully static register indexing; k reads are wave-uniform (broadcast).
// ---------------------------------------------------------------------------
#define CONV_CHUNK(HI, LO)                                                \
  {                                                                       \
    const float4 lv0 = *(const float4*)&Us[base - 8];                     \
    const float4 lv1 = *(const float4*)&Us[base - 4];                     \
    LO[0] = lv0.x; LO[1] = lv0.y; LO[2] = lv0.z; LO[3] = lv0.w;           \
    LO[4] = lv1.x; LO[5] = lv1.y; LO[6] = lv1.z; LO[7] = lv1.w;           \
    const float4 kv0 = *(const float4*)&Ks[m0];                           \
    const float4 kv1 = *(const float4*)&Ks[m0 + 4];                       \
    const float kc[8] = {kv0.x, kv0.y, kv0.z, kv0.w,                      \
                         kv1.x, kv1.y, kv1.z, kv1.w};                     \
    _Pragma("unroll")                                                     \
    for (int mm = 0; mm < 8; ++mm) {                                      \
      _Pragma("unroll")                                                   \
      for (int r = 0; r < 8; ++r) {                                       \
        acc[r] += kc[mm] * ((r >= mm) ? HI[r - mm] : LO[8 + r - mm]);     \
      }                                                                   \
    }                                                                     \
    m0 += 8;                                                              \
    base -= 8;                                                            \
  }

__global__ __launch_bounds__(256) void conv_kernel(
    const float* __restrict__ u, const float* __restrict__ kf,
    const float* __restrict__ D, __hip_bfloat16* __restrict__ g) {
  const int bh = blockIdx.x;  // b*1024 + h
  const int h = bh & (HDIM - 1);
  __shared__ __align__(16) float Us[LFULL];
  __shared__ __align__(16) float Ks[LFULL];
  const int tid = threadIdx.x;
  {
    const float4* us = (const float4*)(u + (size_t)bh * LFULL);
    const float4* ks = (const float4*)(kf + (size_t)h * LFULL);
    for (int i = tid; i < LFULL / 4; i += 256) {
      ((float4*)Us)[i] = us[i];
      ((float4*)Ks)[i] = ks[i];
    }
  }
  __syncthreads();
  const float Dh = D[h];
  float u0[8];
#pragma unroll
  for (int j = 0; j < 8; ++j) u0[j] = Us[j];
  __hip_bfloat16* grow = g + (size_t)bh * LFULL;

  for (int c = 0; c < 4; ++c) {
    const int l0 = 2048 * c + 8 * tid;
    float acc[8], A[8], B[8];
#pragma unroll
    for (int r = 0; r < 8; ++r) {
      A[r] = Us[l0 + r];
      acc[r] = Dh * A[r];
    }
    int m0 = 0;
    int base = l0;
    while (m0 + 16 <= l0) {
      CONV_CHUNK(A, B)
      CONV_CHUNK(B, A)
    }
    if (m0 < l0) CONV_CHUNK(A, B)
    // tail: m = l0 + mm, uses u[0..7]
#pragma unroll
    for (int mm = 0; mm < 8; ++mm) {
      const float km = Ks[l0 + mm];
#pragma unroll
      for (int r = mm; r < 8; ++r) acc[r] += km * u0[r - mm];
    }
    union {
      __hip_bfloat16 hb[8];
      uint4 v;
    } pk;
#pragma unroll
    for (int r = 0; r < 8; ++r) {
      const float y = acc[r];
      const float ge = 0.5f * y * (1.0f + erff(y * 0.70710678118654752f));
      pk.hb[r] = __float2bfloat16(ge);
    }
    *(uint4*)(grow + l0) = pk.v;
  }
}

// ---------------------------------------------------------------------------
// Kernel 3: out[b,o,l] = b_out[o] + sum_h W[o,h] * g[b,h,l]   (fp32 VALU)
// Block tile: 128 o x 64 l, one b. K staged in 32-h chunks.
// Thread micro-tile 8 o x 4 l; lane layout og=tid&15, lg=tid>>4 for broadcast.
// ---------------------------------------------------------------------------
__device__ __forceinline__ float bf16_lo(unsigned v) {
  return __uint_as_float(v << 16);
}
__device__ __forceinline__ float bf16_hi(unsigned v) {
  return __uint_as_float(v & 0xffff0000u);
}

__global__ __launch_bounds__(256) void out_mm_kernel(
    const __hip_bfloat16* __restrict__ g, const float* __restrict__ W,
    const float* __restrict__ bo, float* __restrict__ out) {
  const int l0 = blockIdx.x * 64;
  const int o0 = blockIdx.y * 128;
  const int b = blockIdx.z;
  __shared__ __align__(16) float Ws[32][132];  // [h][o], padded
  __shared__ __align__(16) float Gs[32][68];   // [h][l], padded
  const int tid = threadIdx.x;
  const int og = tid & 15;
  const int lg = tid >> 4;
  float acc[8][4];
#pragma unroll
  for (int j = 0; j < 8; ++j)
#pragma unroll
    for (int r = 0; r < 4; ++r) acc[j][r] = 0.0f;

  const int wo = tid & 127;        // o row for W staging
  const int wh = (tid >> 7) * 16;  // h offset 0 or 16
  const int gr = tid >> 3;         // 0..31 h-row for g staging
  const int gc = (tid & 7) * 8;    // l offset

  for (int h0 = 0; h0 < HDIM; h0 += 32) {
    {  // stage W tile [128 o][32 h] -> Ws[h][o]
      const float* wp = W + (size_t)(o0 + wo) * HDIM + h0 + wh;
      const float4 a0 = *(const float4*)(wp + 0);
      const float4 a1 = *(const float4*)(wp + 4);
      const float4 a2 = *(const float4*)(wp + 8);
      const float4 a3 = *(const float4*)(wp + 12);
      const float tmp[16] = {a0.x, a0.y, a0.z, a0.w, a1.x, a1.y, a1.z, a1.w,
                             a2.x, a2.y, a2.z, a2.w, a3.x, a3.y, a3.z, a3.w};
#pragma unroll
      for (int jj = 0; jj < 16; ++jj) Ws[wh + jj][wo] = tmp[jj];
    }
    {  // stage g tile [32 h][64 l] bf16 -> fp32 Gs[h][l]
      const __hip_bfloat16* gp =
          g + ((size_t)(b * HDIM + h0 + gr)) * LFULL + l0 + gc;
      const uint4 raw = *(const uint4*)gp;
      float gvv[8];
      gvv[0] = bf16_lo(raw.x);
      gvv[1] = bf16_hi(raw.x);
      gvv[2] = bf16_lo(raw.y);
      gvv[3] = bf16_hi(raw.y);
      gvv[4] = bf16_lo(raw.z);
      gvv[5] = bf16_hi(raw.z);
      gvv[6] = bf16_lo(raw.w);
      gvv[7] = bf16_hi(raw.w);
      *(float4*)&Gs[gr][gc] = make_float4(gvv[0], gvv[1], gvv[2], gvv[3]);
      *(float4*)&Gs[gr][gc + 4] = make_float4(gvv[4], gvv[5], gvv[6], gvv[7]);
    }
    __syncthreads();
#pragma unroll 4
    for (int hh = 0; hh < 32; ++hh) {
      const float4 w0 = *(const float4*)&Ws[hh][og * 8];
      const float4 w1 = *(const float4*)&Ws[hh][og * 8 + 4];
      const float4 gv = *(const float4*)&Gs[hh][lg * 4];
      const float wv[8] = {w0.x, w0.y, w0.z, w0.w, w1.x, w1.y, w1.z, w1.w};
      const float gvv[4] = {gv.x, gv.y, gv.z, gv.w};
#pragma unroll
      for (int j = 0; j < 8; ++j)
#pragma unroll
        for (int r = 0; r < 4; ++r) acc[j][r] += wv[j] * gvv[r];
    }
    __syncthreads();
  }
#pragma unroll
  for (int j = 0; j < 8; ++j) {
    const int o = o0 + og * 8 + j;
    const float bias = bo[o];
    float4 res;
    res.x = acc[j][0] + bias;
    res.y = acc[j][1] + bias;
    res.z = acc[j][2] + bias;
    res.w = acc[j][3] + bias;
    *(float4*)(out + ((size_t)(b * HDIM + o)) * LFULL + l0 + lg * 4) = res;
  }
}

// ---------------------------------------------------------------------------
extern "C" void kernel_launch(void* const* d_in, const int* in_sizes, int n_in,
                              void* d_out, int out_size, void* d_ws,
                              size_t ws_size, hipStream_t stream) {
  const float* u = (const float*)d_in[0];     // (4, 1024, 8192)
  const float* kern = (const float*)d_in[1];  // (8, 1, 1024, 64)
  const float* D = (const float*)d_in[2];     // (1, 1024)
  const float* W = (const float*)d_in[3];     // (1024, 1024)
  const float* bo = (const float*)d_in[4];    // (1024,)
  float* out = (float*)d_out;                 // (4, 1024, 8192)

  float* kf = (float*)d_ws;  // 1024*8192 fp32 = 32 MB
  __hip_bfloat16* g =
      (__hip_bfloat16*)((char*)d_ws + (size_t)HDIM * LFULL * sizeof(float));
  // g: 4*1024*8192 bf16 = 64 MB  (ws total 96 MB)

  k_synth_kernel<<<HDIM, 256, 0, stream>>>(kern, kf);
  conv_kernel<<<4 * HDIM, 256, 0, stream>>>(u, kf, D, g);
  out_mm_kernel<<<dim3(LFULL / 64, HDIM / 128, 4), 256, 0, stream>>>(g, W, bo,
                                                                     out);
}

// Round 2
// 596.862 us; speedup vs baseline: 8.7211x; 8.7211x over previous
//
#include <hip/hip_runtime.h>
#include <hip/hip_bf16.h>

#define LFULL 8192
#define HDIM 1024

typedef __attribute__((ext_vector_type(8))) short bf16x8;
typedef __attribute__((ext_vector_type(4))) float f32x4;

union U16 {
  uint4 u;
  bf16x8 s;
  ushort e[8];
};

__device__ __forceinline__ ushort f2bf(float x) {
  union { float f; uint u; } a;
  a.f = x;
  uint r = a.u + 0x7fffu + ((a.u >> 16) & 1u);
  return (ushort)(r >> 16);
}
__device__ __forceinline__ float bf2f(ushort x) {
  union { uint u; float f; } a;
  a.u = ((uint)x) << 16;
  return a.f;
}

__device__ __forceinline__ void gload16(const void* src, void* lds) {
  __builtin_amdgcn_global_load_lds(
      (const __attribute__((address_space(1))) unsigned int*)src,
      (__attribute__((address_space(3))) unsigned int*)lds, 16, 0, 0);
}

// byte-chunk swizzle for Ubf rows: cI = i*8 + kc*4 + q (bits: q=0..1, kc=2, i=3+)
// XOR bit2 with i&1, bits0-1 with (i>>1)&3 -> spreads B-frag reads over 32 banks
#define USWZ(cI) ((cI) ^ ((((cI) >> 3) & 1) << 2) ^ (((cI) >> 4) & 3))

// ---------------------------------------------------------------------------
// Kernel 1: multi-scale kernel synthesis + L2 norm -> bf16 kb[h][8192]
// ---------------------------------------------------------------------------
__global__ __launch_bounds__(256) void k_synth_kernel(
    const float* __restrict__ kern, ushort* __restrict__ kout) {
  const int h = blockIdx.x;
  const int tid = threadIdx.x;
  __shared__ float Kw[8][64];
  __shared__ __align__(16) float kv[LFULL];
  __shared__ float red[8];
  for (int idx = tid; idx < 8 * 64; idx += 256) {
    int i = idx >> 6, j = idx & 63;
    Kw[i][j] = kern[(i * HDIM + h) * 64 + j];
  }
  __syncthreads();
  const float mult = (float)(1.0 + 3.0 * (double)h / 1023.0);
  float pw[8];
  pw[7] = 1.0f;
#pragma unroll
  for (int i = 6; i >= 0; --i) pw[i] = pw[i + 1] * mult;
  float ss = 0.0f;
  for (int m = tid; m < LFULL; m += 256) {
    const int i = (m < 64) ? 0 : (32 - __clz(m >> 6));
    const int slog = (i == 0) ? 0 : (i - 1);
    const float inv_s = 1.0f / (float)(1 << slog);
    const int off = (i == 0) ? 0 : (64 << (i - 1));
    const int t = m - off;
    const float pos = ((float)t + 0.5f) * inv_s - 0.5f;
    const float lof = floorf(pos);
    const float w = pos - lof;
    int lo = (int)lof;
    int hi = lo + 1;
    lo = min(63, max(0, lo));
    hi = min(63, max(0, hi));
    const float val = (Kw[i][lo] * (1.0f - w) + Kw[i][hi] * w) * pw[i];
    kv[m] = val;
    ss += val * val;
  }
#pragma unroll
  for (int o = 32; o > 0; o >>= 1) ss += __shfl_xor(ss, o, 64);
  if ((tid & 63) == 0) red[tid >> 6] = ss;
  __syncthreads();
  if (tid == 0) red[0] = sqrtf(red[0] + red[1] + red[2] + red[3]);
  __syncthreads();
  const float inv_norm = 1.0f / red[0];
  ushort* krow = kout + ((size_t)h << 13);
  for (int m = tid; m < LFULL; m += 256) krow[m] = f2bf(kv[m] * inv_norm);
}

// ---------------------------------------------------------------------------
// Kernel 2: causal conv as block-Toeplitz MFMA + skip + GELU -> bf16 g[b][h][l]
// Block: 512 thr (8 waves), 2 h. Waves 0-3 -> h0, 4-7 -> h1.
// l-blocks T=64 (i=0..127), Y_i += K_d * U_{i-d}, K_d[r][c]=k[64d+r-c].
// Wave w' owns frags (g=0..7, b=(g+w')&3): per-d balanced triangular skip.
// ---------------------------------------------------------------------------
__device__ __forceinline__ void buildA(int dd, ushort* Abuf,
                                       const ushort* Kring, int tid) {
  uint4* Ab4 = (uint4*)Abuf;
  const int buf = dd & 1;
  for (int c = tid; c < 768; c += 512) {
    const int hb = c / 384;
    const int rem = c - hb * 384;
    const int s = rem >> 6;
    const int lane = rem & 63;
    const int rr = lane & 15, q = lane >> 4;
    const int start = (dd << 6) + (s << 4) - 32 + rr - (q << 3);
    U16 pk;
#pragma unroll
    for (int j = 0; j < 8; ++j) {
      const int idx = start - j;
      const int ra = ((idx >> 6) & 3) * 128 + hb * 64 + (idx & 63);
      const ushort v = Kring[ra];
      pk.e[j] = (idx >= 0) ? v : (ushort)0;
    }
    Ab4[((buf * 2 + hb) * 6 + s) * 64 + lane] = pk.u;
  }
}

__global__ __launch_bounds__(512, 2) void conv_mfma_kernel(
    const float* __restrict__ u, const ushort* __restrict__ kb,
    const float* __restrict__ Dp, ushort* __restrict__ g) {
  __shared__ __align__(16) ushort Ubf[8 * LFULL];       // 128 KB
  __shared__ __align__(16) ushort Kring[4 * 2 * 64];    // 1 KB ring
  __shared__ __align__(16) ushort Abuf[2 * 2 * 6 * 64 * 8];  // 24 KB dbuf
  const int tid = threadIdx.x;
  const int h0 = blockIdx.x * 2;
  uint4* Ub4 = (uint4*)Ubf;

  // stage u: fp32 -> bf16, swizzled 16B chunks. row = hl*4 + b.
  for (int c = tid; c < 8192; c += 512) {
    const int row = c >> 10;
    const int cI = c & 1023;
    const int hl = row >> 2, b = row & 3;
    const float* up = u + (((size_t)(b * HDIM + h0 + hl)) << 13) + (cI << 3);
    const float4 v0 = *(const float4*)up;
    const float4 v1 = *(const float4*)(up + 4);
    U16 pk;
    pk.e[0] = f2bf(v0.x); pk.e[1] = f2bf(v0.y);
    pk.e[2] = f2bf(v0.z); pk.e[3] = f2bf(v0.w);
    pk.e[4] = f2bf(v1.x); pk.e[5] = f2bf(v1.y);
    pk.e[6] = f2bf(v1.z); pk.e[7] = f2bf(v1.w);
    Ub4[(row << 10) + USWZ(cI)] = pk.u;
  }
  // prologue: k chunks 0,1 into ring bufs 0,1
  if (tid < 32) {
    const int ch = tid >> 4, hh = (tid >> 3) & 1, e = tid & 7;
    gload16(kb + (((size_t)(h0 + hh)) << 13) + ch * 64 + e * 8, Kring);
  }
  __syncthreads();  // drains vmcnt (k chunks) + lgkm (u staging)
  buildA(0, Abuf, Kring, tid);
  __syncthreads();

  const int w = tid >> 6, lane = tid & 63;
  const int hl = w >> 2, wp = w & 3;
  const int col = lane & 15, q = lane >> 4;
  f32x4 acc[8][4];
#pragma unroll
  for (int f = 0; f < 8; ++f)
#pragma unroll
    for (int m = 0; m < 4; ++m) acc[f][m] = (f32x4){0.f, 0.f, 0.f, 0.f};

  for (int d = 0; d < 128; ++d) {
    // prefetch k chunk d+2 into ring slot (d+2)&3
    if (tid < 16 && d + 2 < 128) {
      const int hh = tid >> 3, e = tid & 7;
      gload16(kb + (((size_t)(h0 + hh)) << 13) + (d + 2) * 64 + e * 8,
              Kring + ((d + 2) & 3) * 128);
    }
    if (d + 1 < 128) buildA(d + 1, Abuf, Kring, tid);
    // compute(d) from Abuf[d&1]
    const int abase = ((d & 1) * 2 + hl) * 6 * 64;
    bf16x8 a[6];
#pragma unroll
    for (int s = 0; s < 6; ++s)
      a[s] = ((const bf16x8*)Abuf)[abase + s * 64 + lane];
#pragma unroll
    for (int f = 0; f < 8; ++f) {
      if (d <= f * 16 + 15) {
        const int b = (f + wp) & 3;
        const int row = (hl << 2) + b;
        const int i = (f << 4) + col;
        const int jb = i - d;
        const int jc = (jb >= 0) ? jb : 0;
        U16 b0, b1;
        b0.u = Ub4[(row << 10) + USWZ((jc << 3) + q)];
        b1.u = Ub4[(row << 10) + USWZ((jc << 3) + 4 + q)];
        if (jb < 0) {
          b0.u = make_uint4(0, 0, 0, 0);
          b1.u = make_uint4(0, 0, 0, 0);
        }
#pragma unroll
        for (int mr = 0; mr < 4; ++mr) {
          acc[f][mr] = __builtin_amdgcn_mfma_f32_16x16x32_bf16(
              a[mr + 2], b0.s, acc[f][mr], 0, 0, 0);  // kc=0: s=mr+2
          acc[f][mr] = __builtin_amdgcn_mfma_f32_16x16x32_bf16(
              a[mr], b1.s, acc[f][mr], 0, 0, 0);      // kc=1: s=mr
        }
      }
    }
    __syncthreads();
  }

  // epilogue: += D*u, exact GELU, bf16 store
  const float Dh = Dp[h0 + hl];
#pragma unroll
  for (int f = 0; f < 8; ++f) {
    const int b = (f + wp) & 3;
    const int row = (hl << 2) + b;
    const int i = (f << 4) + col;
    ushort* gp = g + (((size_t)(b * HDIM + h0 + hl)) << 13);
#pragma unroll
    for (int mr = 0; mr < 4; ++mr) {
      const int cI = (i << 3) + (mr << 1) + (q >> 1);
      const ushort* ub =
          Ubf + (((row << 10) + USWZ(cI)) << 3) + ((q & 1) << 2);
      const uint2 uv = *(const uint2*)ub;
      float uu[4];
      uu[0] = bf2f((ushort)(uv.x & 0xffff));
      uu[1] = bf2f((ushort)(uv.x >> 16));
      uu[2] = bf2f((ushort)(uv.y & 0xffff));
      uu[3] = bf2f((ushort)(uv.y >> 16));
      ushort o[4];
#pragma unroll
      for (int v = 0; v < 4; ++v) {
        const float y = acc[f][mr][v] + Dh * uu[v];
        const float ge = 0.5f * y * (1.0f + erff(y * 0.70710678118654752f));
        o[v] = f2bf(ge);
      }
      uint2 outp;
      outp.x = (uint)o[0] | ((uint)o[1] << 16);
      outp.y = (uint)o[2] | ((uint)o[3] << 16);
      *(uint2*)(gp + (i << 6) + (mr << 4) + (q << 2)) = outp;
    }
  }
}

// ---------------------------------------------------------------------------
// Kernel 3: transpose g[b][h][l] -> gt[b][l][h] (64x64 tiles, XOR-swizzled LDS)
// ---------------------------------------------------------------------------
__global__ __launch_bounds__(256) void transpose_kernel(
    const ushort* __restrict__ g, ushort* __restrict__ gt) {
  __shared__ __align__(16) ushort Ts[64 * 64];
  const int l0 = blockIdx.x * 64, hh0 = blockIdx.y * 64, b = blockIdx.z;
  const int tid = threadIdx.x;
#pragma unroll
  for (int p = 0; p < 2; ++p) {
    const int hh = (tid >> 3) + 32 * p;
    const int c8 = tid & 7;
    const uint4 v = *(const uint4*)(g + (((size_t)(b * HDIM + hh0 + hh)) << 13)
                                    + l0 + c8 * 8);
    ((uint4*)Ts)[hh * 8 + (c8 ^ ((hh >> 3) & 7))] = v;
  }
  __syncthreads();
#pragma unroll
  for (int p = 0; p < 2; ++p) {
    const int lr = (tid >> 3) + 32 * p;
    const int o8 = tid & 7;
    U16 pk;
#pragma unroll
    for (int j = 0; j < 8; ++j) {
      const int hq = o8 * 8 + j;
      pk.e[j] = Ts[hq * 64 + (((lr >> 3) ^ o8) << 3) + (lr & 7)];
    }
    ((uint4*)(gt + ((size_t)b * LFULL + l0 + lr) * HDIM + hh0))[o8] = pk.u;
  }
}

// ---------------------------------------------------------------------------
// Kernel 4: W fp32 -> bf16
// ---------------------------------------------------------------------------
__global__ __launch_bounds__(256) void wcvt_kernel(const float* __restrict__ W,
                                                   ushort* __restrict__ Wb) {
  const int i = (blockIdx.x * 256 + threadIdx.x) * 8;
  const float4 v0 = *(const float4*)(W + i);
  const float4 v1 = *(const float4*)(W + i + 4);
  U16 pk;
  pk.e[0] = f2bf(v0.x); pk.e[1] = f2bf(v0.y);
  pk.e[2] = f2bf(v0.z); pk.e[3] = f2bf(v0.w);
  pk.e[4] = f2bf(v1.x); pk.e[5] = f2bf(v1.y);
  pk.e[6] = f2bf(v1.z); pk.e[7] = f2bf(v1.w);
  ((uint4*)Wb)[i >> 3] = pk.u;
}

// ---------------------------------------------------------------------------
// Kernel 5: out[b,o,l] = bo[o] + sum_h Wb[o,h]*gt[b,l,h]  (128x128 MFMA GEMM)
// ---------------------------------------------------------------------------
__global__ __launch_bounds__(256, 2) void outmm_kernel(
    const ushort* __restrict__ Wb, const ushort* __restrict__ gt,
    const float* __restrict__ bo, float* __restrict__ out) {
  __shared__ __align__(16) ushort As[128 * 32];
  __shared__ __align__(16) ushort Bs[128 * 32];
  const int tid = threadIdx.x;
  const int l0 = blockIdx.x * 128, o0 = blockIdx.y * 128, b = blockIdx.z;
  const int w = tid >> 6, lane = tid & 63;
  const int wm = w >> 1, wn = w & 1;
  const int col = lane & 15, q = lane >> 4;
  const int srow = lane >> 2, scol = (lane & 3) * 8;
  f32x4 acc[4][4];
#pragma unroll
  for (int m = 0; m < 4; ++m)
#pragma unroll
    for (int n = 0; n < 4; ++n) acc[m][n] = (f32x4){0.f, 0.f, 0.f, 0.f};
  const ushort* gb = gt + ((size_t)b * LFULL) * HDIM;
  for (int kt = 0; kt < 32; ++kt) {
    const int k0 = kt * 32;
    const int r0 = w * 32;
#pragma unroll
    for (int ii = 0; ii < 2; ++ii) {
      const int ra = r0 + ii * 16 + srow;
      gload16(Wb + (size_t)(o0 + ra) * HDIM + k0 + scol,
              As + (r0 + ii * 16) * 32);
      gload16(gb + (size_t)(l0 + ra) * HDIM + k0 + scol,
              Bs + (r0 + ii * 16) * 32);
    }
    __syncthreads();
    bf16x8 aa[4], bb[4];
#pragma unroll
    for (int m = 0; m < 4; ++m) {
      aa[m] = ((const bf16x8*)As)[(wm * 64 + m * 16 + col) * 4 + q];
      bb[m] = ((const bf16x8*)Bs)[(wn * 64 + m * 16 + col) * 4 + q];
    }
#pragma unroll
    for (int m = 0; m < 4; ++m)
#pragma unroll
      for (int n = 0; n < 4; ++n)
        acc[m][n] = __builtin_amdgcn_mfma_f32_16x16x32_bf16(aa[m], bb[n],
                                                            acc[m][n], 0, 0, 0);
    __syncthreads();
  }
#pragma unroll
  for (int m = 0; m < 4; ++m) {
    const int ob = o0 + wm * 64 + m * 16 + q * 4;
    const float4 bv = *(const float4*)(bo + ob);
    const float bva[4] = {bv.x, bv.y, bv.z, bv.w};
#pragma unroll
    for (int n = 0; n < 4; ++n) {
      const int l = l0 + wn * 64 + n * 16 + col;
      float* op = out + (((size_t)(b * HDIM + ob)) << 13) + l;
#pragma unroll
      for (int v = 0; v < 4; ++v) op[(size_t)v << 13] = acc[m][n][v] + bva[v];
    }
  }
}

// ---------------------------------------------------------------------------
extern "C" void kernel_launch(void* const* d_in, const int* in_sizes, int n_in,
                              void* d_out, int out_size, void* d_ws,
                              size_t ws_size, hipStream_t stream) {
  const float* u = (const float*)d_in[0];     // (4, 1024, 8192)
  const float* kern = (const float*)d_in[1];  // (8, 1, 1024, 64)
  const float* D = (const float*)d_in[2];     // (1, 1024)
  const float* W = (const float*)d_in[3];     // (1024, 1024)
  const float* bo = (const float*)d_in[4];    // (1024,)
  float* out = (float*)d_out;                 // (4, 1024, 8192)

  char* ws = (char*)d_ws;
  ushort* kb = (ushort*)ws;                              // 16 MB
  ushort* g = (ushort*)(ws + (size_t)16 * 1024 * 1024);  // 64 MB
  ushort* gt = (ushort*)(ws + (size_t)80 * 1024 * 1024); // 64 MB
  ushort* Wb = (ushort*)(ws + (size_t)144 * 1024 * 1024);// 2 MB

  k_synth_kernel<<<HDIM, 256, 0, stream>>>(kern, kb);
  wcvt_kernel<<<512, 256, 0, stream>>>(W, Wb);
  conv_mfma_kernel<<<512, 512, 0, stream>>>(u, kb, D, g);
  transpose_kernel<<<dim3(128, 16, 4), 256, 0, stream>>>(g, gt);
  outmm_kernel<<<dim3(64, 8, 4), 256, 0, stream>>>(Wb, gt, bo, out);
}

// Round 3
// 496.471 us; speedup vs baseline: 10.4846x; 1.2022x over previous
//
#include <hip/hip_runtime.h>
#include <hip/hip_bf16.h>

#define LFULL 8192
#define HDIM 1024
#define KPAD 8320  // 65 chunks of 128 elems (last chunk zeros)

typedef __attribute__((ext_vector_type(8))) short bf16x8;
typedef __attribute__((ext_vector_type(4))) float f32x4;
typedef __attribute__((ext_vector_type(16))) float f32x16;

union U16 {
  uint4 u;
  bf16x8 s;
  ushort e[8];
};

__device__ __forceinline__ ushort f2bf(float x) {
  union { float f; uint u; } a;
  a.f = x;
  uint r = a.u + 0x7fffu + ((a.u >> 16) & 1u);
  return (ushort)(r >> 16);
}
__device__ __forceinline__ float bf2f(ushort x) {
  union { uint u; float f; } a;
  a.u = ((uint)x) << 16;
  return a.f;
}

__device__ __forceinline__ void gload16(const void* src, void* lds) {
  __builtin_amdgcn_global_load_lds(
      (const __attribute__((address_space(1))) unsigned int*)src,
      (__attribute__((address_space(3))) unsigned int*)lds, 16, 0, 0);
}
__device__ __forceinline__ void gload4(const void* src, void* lds) {
  __builtin_amdgcn_global_load_lds(
      (const __attribute__((address_space(1))) unsigned int*)src,
      (__attribute__((address_space(3))) unsigned int*)lds, 4, 0, 0);
}

__device__ __forceinline__ uint ALIGNB(uint hi, uint lo, uint sh) {
#if __has_builtin(__builtin_amdgcn_alignbyte)
  return __builtin_amdgcn_alignbyte(hi, lo, sh);
#else
  return (uint)((((unsigned long long)hi << 32) | (unsigned long long)lo) >> (8u * sh));
#endif
}

// ---------------------------------------------------------------------------
// Kernel 1: multi-scale kernel synthesis + L2 norm -> bf16 kbrev[h][8320]
// kbrev[h][x] = k_norm[h][8191-x], zeros for x >= 8192.
// ---------------------------------------------------------------------------
__global__ __launch_bounds__(256) void k_synth_kernel(
    const float* __restrict__ kern, ushort* __restrict__ kout) {
  const int h = blockIdx.x;
  const int tid = threadIdx.x;
  __shared__ float Kw[8][64];
  __shared__ __align__(16) float kv[LFULL];
  __shared__ float red[8];
  for (int idx = tid; idx < 8 * 64; idx += 256) {
    int i = idx >> 6, j = idx & 63;
    Kw[i][j] = kern[(i * HDIM + h) * 64 + j];
  }
  __syncthreads();
  const float mult = (float)(1.0 + 3.0 * (double)h / 1023.0);
  float pw[8];
  pw[7] = 1.0f;
#pragma unroll
  for (int i = 6; i >= 0; --i) pw[i] = pw[i + 1] * mult;
  float ss = 0.0f;
  for (int m = tid; m < LFULL; m += 256) {
    const int i = (m < 64) ? 0 : (32 - __clz(m >> 6));
    const int slog = (i == 0) ? 0 : (i - 1);
    const float inv_s = 1.0f / (float)(1 << slog);
    const int off = (i == 0) ? 0 : (64 << (i - 1));
    const int t = m - off;
    const float pos = ((float)t + 0.5f) * inv_s - 0.5f;
    const float lof = floorf(pos);
    const float wgt = pos - lof;
    int lo = (int)lof;
    int hi = lo + 1;
    lo = min(63, max(0, lo));
    hi = min(63, max(0, hi));
    const float val = (Kw[i][lo] * (1.0f - wgt) + Kw[i][hi] * wgt) * pw[i];
    kv[m] = val;
    ss += val * val;
  }
#pragma unroll
  for (int o = 32; o > 0; o >>= 1) ss += __shfl_xor(ss, o, 64);
  if ((tid & 63) == 0) red[tid >> 6] = ss;
  __syncthreads();
  if (tid == 0) red[0] = sqrtf(red[0] + red[1] + red[2] + red[3]);
  __syncthreads();
  const float inv_norm = 1.0f / red[0];
  ushort* krow = kout + (size_t)h * KPAD;
  for (int m = tid; m < LFULL; m += 256) krow[8191 - m] = f2bf(kv[m] * inv_norm);
  if (tid < 128) krow[8192 + tid] = 0;
}

// ---------------------------------------------------------------------------
// Kernel 2: causal conv via block-Toeplitz 32x32x16 MFMA. Block = 1 h, 4
// waves (one per b). No barriers in main loop. A-windows built per-wave from
// a kbrev LDS ring (global_load_lds streamed, vmcnt-counted). u bf16 in LDS,
// XOR chunk swizzle. Epilogue: skip D*u + exact GELU -> bf16 g[b][h][l].
// ---------------------------------------------------------------------------
__global__ __launch_bounds__(256, 2) void conv_mfma_kernel(
    const float* __restrict__ u, const ushort* __restrict__ kbrev,
    const float* __restrict__ Dp, ushort* __restrict__ g) {
  __shared__ __align__(16) ushort Us[4 * LFULL];  // 64 KB
  __shared__ __align__(16) ushort Ring[4][640];   // per-wave kbrev rings
  const int tid = threadIdx.x;
  const int h = blockIdx.x;
  const int w = tid >> 6;  // wave index == b
  const int lane = tid & 63;
  const int c32 = lane & 31;
  const int qh = lane >> 5;
  uint4* Us4 = (uint4*)Us;

  // ---- stage u: fp32 -> bf16, swizzled 16B chunks ----
  for (int cc = tid; cc < 4096; cc += 256) {
    const int row = cc >> 10, cI = cc & 1023;
    const float* up = u + (((size_t)(row * HDIM + h)) << 13) + (cI << 3);
    const float4 v0 = *(const float4*)up;
    const float4 v1 = *(const float4*)(up + 4);
    U16 pk;
    pk.e[0] = f2bf(v0.x); pk.e[1] = f2bf(v0.y);
    pk.e[2] = f2bf(v0.z); pk.e[3] = f2bf(v0.w);
    pk.e[4] = f2bf(v1.x); pk.e[5] = f2bf(v1.y);
    pk.e[6] = f2bf(v1.z); pk.e[7] = f2bf(v1.w);
    const int phys = (cI & ~7) | ((cI & 7) ^ ((cI >> 3) & 7));
    Us4[(row << 10) + phys] = pk.u;
  }

  // ---- ring prologue: chunks 64,63,62 (+dup of 64 at phys 512) ----
  const ushort* kr = kbrev + (size_t)h * KPAD;
  ushort* ring = (ushort*)Ring[w];
  gload4(kr + 64 * 128 + 2 * lane, ring + 0 * 128);
  gload4(kr + 63 * 128 + 2 * lane, ring + 3 * 128);
  gload4(kr + 62 * 128 + 2 * lane, ring + 2 * 128);
  gload4(kr + 64 * 128 + 2 * lane, ring + 512);
  __syncthreads();
  asm volatile("s_waitcnt vmcnt(0)" ::: "memory");
  __builtin_amdgcn_sched_barrier(0);

  f32x16 acc[4][2];
#pragma unroll
  for (int f = 0; f < 4; ++f)
#pragma unroll
    for (int rg = 0; rg < 2; ++rg)
#pragma unroll
      for (int q = 0; q < 16; ++q) acc[f][rg][q] = 0.0f;

  const uint shby = ((uint)((c32 & 1) ^ 1)) * 2u;  // byte shift for extract
  int Pb = 8191 - c32 + 8 * qh;  // kbrev index for m=0 at current d
  int dcnt = 61;                 // next chunk to stream

  for (int d = 0; d < 128; ++d) {
    if ((d & 1) == 0) {
      const int c = dcnt < 0 ? 0 : dcnt;
      gload4(kr + c * 128 + 2 * lane, ring + (c & 3) * 128);
      gload4(kr + c * 128 + 2 * lane,
             ring + (((c & 3) == 0) ? 512 : (c & 3) * 128));
      dcnt--;
      asm volatile("s_waitcnt vmcnt(2)" ::: "memory");
      __builtin_amdgcn_sched_barrier(0);
    }
    // build 6 A-windows: W[mm][lane][j] = k[64d + 16*(mm-3) + c32 - 8*qh - j]
    bf16x8 W[6];
#pragma unroll
    for (int mm = 0; mm < 6; ++mm) {
      const int P = Pb + 48 - 16 * mm;
      const int pos = (P & ~1) & 511;
      const ushort* rp = ring + pos;
      const uint dw0 = *(const uint*)(rp);
      const uint dw1 = *(const uint*)(rp + 2);
      const uint dw2 = *(const uint*)(rp + 4);
      const uint dw3 = *(const uint*)(rp + 6);
      const uint dw4 = *(const uint*)(rp + 8);
      U16 wv;
      wv.u.x = ALIGNB(dw1, dw0, shby);
      wv.u.y = ALIGNB(dw2, dw1, shby);
      wv.u.z = ALIGNB(dw3, dw2, shby);
      wv.u.w = ALIGNB(dw4, dw3, shby);
      W[mm] = wv.s;
    }
    const int dc = d >> 5, dl = d & 31;
#pragma unroll
    for (int f = 0; f < 4; ++f) {
      if (f >= dc) {
        const int j0 = f * 32 + c32 - d;
        const int jc = j0 < 0 ? 0 : j0;
        const int m8 = jc & 7;
        const uint4* ub = Us4 + (w << 10) + (jc << 3);
        uint4 B[4];
#pragma unroll
        for (int ks = 0; ks < 4; ++ks) B[ks] = ub[(2 * ks + qh) ^ m8];
        if (f == dc && dl != 0) {
          const bool kp = (c32 >= dl);
#pragma unroll
          for (int ks = 0; ks < 4; ++ks) {
            B[ks].x = kp ? B[ks].x : 0u;
            B[ks].y = kp ? B[ks].y : 0u;
            B[ks].z = kp ? B[ks].z : 0u;
            B[ks].w = kp ? B[ks].w : 0u;
          }
        }
#pragma unroll
        for (int rg = 0; rg < 2; ++rg) {
#pragma unroll
          for (int ks = 0; ks < 4; ++ks) {
            U16 bb;
            bb.u = B[ks];
            acc[f][rg] = __builtin_amdgcn_mfma_f32_32x32x16_bf16(
                W[2 * rg - ks + 3], bb.s, acc[f][rg], 0, 0, 0);
          }
        }
      }
    }
    Pb -= 64;
  }

  // ---- epilogue: += D*u, exact GELU, bf16 store ----
  const float Dh = Dp[h];
  ushort* gp = g + (((size_t)(w * HDIM + h)) << 13);
#pragma unroll
  for (int f = 0; f < 4; ++f) {
#pragma unroll
    for (int rg = 0; rg < 2; ++rg) {
      const int lbase = (f * 32 + c32) * 64 + rg * 32 + 4 * qh;
#pragma unroll
      for (int rq = 0; rq < 4; ++rq) {
        const int l = lbase + 8 * rq;
        const int cI = l >> 3;
        const int phys = (cI & ~7) | ((cI & 7) ^ ((cI >> 3) & 7));
        const uint2 uv =
            *(const uint2*)(Us + (w << 13) + (phys << 3) + 4 * qh);
        float uu[4];
        uu[0] = bf2f((ushort)(uv.x & 0xffff));
        uu[1] = bf2f((ushort)(uv.x >> 16));
        uu[2] = bf2f((ushort)(uv.y & 0xffff));
        uu[3] = bf2f((ushort)(uv.y >> 16));
        ushort o[4];
#pragma unroll
        for (int jj = 0; jj < 4; ++jj) {
          const float y = acc[f][rg][rq * 4 + jj] + Dh * uu[jj];
          const float ge = 0.5f * y * (1.0f + erff(y * 0.70710678118654752f));
          o[jj] = f2bf(ge);
        }
        uint2 op;
        op.x = (uint)o[0] | ((uint)o[1] << 16);
        op.y = (uint)o[2] | ((uint)o[3] << 16);
        *(uint2*)(gp + l) = op;
      }
    }
  }
}

// ---------------------------------------------------------------------------
// Kernel 3: transpose g[b][h][l] -> gt[b][l][h] (64x64 tiles, XOR-swizzled)
// ---------------------------------------------------------------------------
__global__ __launch_bounds__(256) void transpose_kernel(
    const ushort* __restrict__ g, ushort* __restrict__ gt) {
  __shared__ __align__(16) ushort Ts[64 * 64];
  const int l0 = blockIdx.x * 64, hh0 = blockIdx.y * 64, b = blockIdx.z;
  const int tid = threadIdx.x;
#pragma unroll
  for (int p = 0; p < 2; ++p) {
    const int hh = (tid >> 3) + 32 * p;
    const int c8 = tid & 7;
    const uint4 v = *(const uint4*)(g + (((size_t)(b * HDIM + hh0 + hh)) << 13)
                                    + l0 + c8 * 8);
    ((uint4*)Ts)[hh * 8 + (c8 ^ ((hh >> 3) & 7))] = v;
  }
  __syncthreads();
#pragma unroll
  for (int p = 0; p < 2; ++p) {
    const int lr = (tid >> 3) + 32 * p;
    const int o8 = tid & 7;
    U16 pk;
#pragma unroll
    for (int j = 0; j < 8; ++j) {
      const int hq = o8 * 8 + j;
      pk.e[j] = Ts[hq * 64 + (((lr >> 3) ^ o8) << 3) + (lr & 7)];
    }
    ((uint4*)(gt + ((size_t)b * LFULL + l0 + lr) * HDIM + hh0))[o8] = pk.u;
  }
}

// ---------------------------------------------------------------------------
// Kernel 4: W fp32 -> bf16
// ---------------------------------------------------------------------------
__global__ __launch_bounds__(256) void wcvt_kernel(const float* __restrict__ W,
                                                   ushort* __restrict__ Wb) {
  const int i = (blockIdx.x * 256 + threadIdx.x) * 8;
  const float4 v0 = *(const float4*)(W + i);
  const float4 v1 = *(const float4*)(W + i + 4);
  U16 pk;
  pk.e[0] = f2bf(v0.x); pk.e[1] = f2bf(v0.y);
  pk.e[2] = f2bf(v0.z); pk.e[3] = f2bf(v0.w);
  pk.e[4] = f2bf(v1.x); pk.e[5] = f2bf(v1.y);
  pk.e[6] = f2bf(v1.z); pk.e[7] = f2bf(v1.w);
  ((uint4*)Wb)[i >> 3] = pk.u;
}

// ---------------------------------------------------------------------------
// Kernel 5: out[b,o,l] = bo[o] + sum_h Wb[o,h]*gt[b,l,h]  (128x128 MFMA GEMM)
// ---------------------------------------------------------------------------
__global__ __launch_bounds__(256, 2) void outmm_kernel(
    const ushort* __restrict__ Wb, const ushort* __restrict__ gt,
    const float* __restrict__ bo, float* __restrict__ out) {
  __shared__ __align__(16) ushort As[128 * 32];
  __shared__ __align__(16) ushort Bs[128 * 32];
  const int tid = threadIdx.x;
  const int l0 = blockIdx.x * 128, o0 = blockIdx.y * 128, b = blockIdx.z;
  const int w = tid >> 6, lane = tid & 63;
  const int wm = w >> 1, wn = w & 1;
  const int col = lane & 15, q = lane >> 4;
  const int srow = lane >> 2, scol = (lane & 3) * 8;
  f32x4 acc[4][4];
#pragma unroll
  for (int m = 0; m < 4; ++m)
#pragma unroll
    for (int n = 0; n < 4; ++n) acc[m][n] = (f32x4){0.f, 0.f, 0.f, 0.f};
  const ushort* gb = gt + ((size_t)b * LFULL) * HDIM;
  for (int kt = 0; kt < 32; ++kt) {
    const int k0 = kt * 32;
    const int r0 = w * 32;
#pragma unroll
    for (int ii = 0; ii < 2; ++ii) {
      const int ra = r0 + ii * 16 + srow;
      gload16(Wb + (size_t)(o0 + ra) * HDIM + k0 + scol,
              As + (r0 + ii * 16) * 32);
      gload16(gb + (size_t)(l0 + ra) * HDIM + k0 + scol,
              Bs + (r0 + ii * 16) * 32);
    }
    __syncthreads();
    bf16x8 aa[4], bb[4];
#pragma unroll
    for (int m = 0; m < 4; ++m) {
      aa[m] = ((const bf16x8*)As)[(wm * 64 + m * 16 + col) * 4 + q];
      bb[m] = ((const bf16x8*)Bs)[(wn * 64 + m * 16 + col) * 4 + q];
    }
#pragma unroll
    for (int m = 0; m < 4; ++m)
#pragma unroll
      for (int n = 0; n < 4; ++n)
        acc[m][n] = __builtin_amdgcn_mfma_f32_16x16x32_bf16(aa[m], bb[n],
                                                            acc[m][n], 0, 0, 0);
    __syncthreads();
  }
#pragma unroll
  for (int m = 0; m < 4; ++m) {
    const int ob = o0 + wm * 64 + m * 16 + q * 4;
    const float4 bv = *(const float4*)(bo + ob);
    const float bva[4] = {bv.x, bv.y, bv.z, bv.w};
#pragma unroll
    for (int n = 0; n < 4; ++n) {
      const int l = l0 + wn * 64 + n * 16 + col;
      float* op = out + (((size_t)(b * HDIM + ob)) << 13) + l;
#pragma unroll
      for (int v = 0; v < 4; ++v) op[(size_t)v << 13] = acc[m][n][v] + bva[v];
    }
  }
}

// ---------------------------------------------------------------------------
extern "C" void kernel_launch(void* const* d_in, const int* in_sizes, int n_in,
                              void* d_out, int out_size, void* d_ws,
                              size_t ws_size, hipStream_t stream) {
  const float* u = (const float*)d_in[0];     // (4, 1024, 8192)
  const float* kern = (const float*)d_in[1];  // (8, 1, 1024, 64)
  const float* D = (const float*)d_in[2];     // (1, 1024)
  const float* W = (const float*)d_in[3];     // (1024, 1024)
  const float* bo = (const float*)d_in[4];    // (1024,)
  float* out = (float*)d_out;                 // (4, 1024, 8192)

  char* ws = (char*)d_ws;
  ushort* g = (ushort*)ws;                                 // [0, 64 MiB)
  ushort* gt = (ushort*)(ws + ((size_t)64 << 20));         // [64, 128 MiB)
  ushort* kbrev = (ushort*)(ws + ((size_t)128 << 20));     // [128, ~144.3 MiB)
  ushort* Wb = (ushort*)(ws + ((size_t)128 << 20));        // reuses kbrev region

  k_synth_kernel<<<HDIM, 256, 0, stream>>>(kern, kbrev);
  conv_mfma_kernel<<<HDIM, 256, 0, stream>>>(u, kbrev, D, g);
  // kbrev dead from here; Wb overlays it.
  wcvt_kernel<<<512, 256, 0, stream>>>(W, Wb);
  transpose_kernel<<<dim3(128, 16, 4), 256, 0, stream>>>(g, gt);
  outmm_kernel<<<dim3(64, 8, 4), 256, 0, stream>>>(Wb, gt, bo, out);
}

// Round 4
// 479.976 us; speedup vs baseline: 10.8450x; 1.0344x over previous
//
#include <hip/hip_runtime.h>
#include <hip/hip_bf16.h>

#define LFULL 8192
#define HDIM 1024
#define KPAD 8320  // 65 chunks of 128 elems (last chunk zeros)

typedef __attribute__((ext_vector_type(8))) short bf16x8;
typedef __attribute__((ext_vector_type(4))) float f32x4;
typedef __attribute__((ext_vector_type(16))) float f32x16;

union U16 {
  uint4 u;
  bf16x8 s;
  ushort e[8];
};

__device__ __forceinline__ ushort f2bf(float x) {
  union { float f; uint u; } a;
  a.f = x;
  uint r = a.u + 0x7fffu + ((a.u >> 16) & 1u);
  return (ushort)(r >> 16);
}
__device__ __forceinline__ float bf2f(ushort x) {
  union { uint u; float f; } a;
  a.u = ((uint)x) << 16;
  return a.f;
}

__device__ __forceinline__ void gload16(const void* src, void* lds) {
  __builtin_amdgcn_global_load_lds(
      (const __attribute__((address_space(1))) unsigned int*)src,
      (__attribute__((address_space(3))) unsigned int*)lds, 16, 0, 0);
}

__device__ __forceinline__ uint ALIGNB(uint hi, uint lo, uint sh) {
#if __has_builtin(__builtin_amdgcn_alignbyte)
  return __builtin_amdgcn_alignbyte(hi, lo, sh);
#else
  return (uint)((((unsigned long long)hi << 32) | (unsigned long long)lo) >> (8u * sh));
#endif
}

// ---------------------------------------------------------------------------
// Kernel 1: multi-scale kernel synthesis + L2 norm -> bf16 kbrev[h][8320]
// kbrev[h][x] = k_norm[h][8191-x], zeros for x >= 8192.
// ---------------------------------------------------------------------------
__global__ __launch_bounds__(256) void k_synth_kernel(
    const float* __restrict__ kern, ushort* __restrict__ kout) {
  const int h = blockIdx.x;
  const int tid = threadIdx.x;
  __shared__ float Kw[8][64];
  __shared__ __align__(16) float kv[LFULL];
  __shared__ float red[8];
  for (int idx = tid; idx < 8 * 64; idx += 256) {
    int i = idx >> 6, j = idx & 63;
    Kw[i][j] = kern[(i * HDIM + h) * 64 + j];
  }
  __syncthreads();
  const float mult = (float)(1.0 + 3.0 * (double)h / 1023.0);
  float pw[8];
  pw[7] = 1.0f;
#pragma unroll
  for (int i = 6; i >= 0; --i) pw[i] = pw[i + 1] * mult;
  float ss = 0.0f;
  for (int m = tid; m < LFULL; m += 256) {
    const int i = (m < 64) ? 0 : (32 - __clz(m >> 6));
    const int slog = (i == 0) ? 0 : (i - 1);
    const float inv_s = 1.0f / (float)(1 << slog);
    const int off = (i == 0) ? 0 : (64 << (i - 1));
    const int t = m - off;
    const float pos = ((float)t + 0.5f) * inv_s - 0.5f;
    const float lof = floorf(pos);
    const float wgt = pos - lof;
    int lo = (int)lof;
    int hi = lo + 1;
    lo = min(63, max(0, lo));
    hi = min(63, max(0, hi));
    const float val = (Kw[i][lo] * (1.0f - wgt) + Kw[i][hi] * wgt) * pw[i];
    kv[m] = val;
    ss += val * val;
  }
#pragma unroll
  for (int o = 32; o > 0; o >>= 1) ss += __shfl_xor(ss, o, 64);
  if ((tid & 63) == 0) red[tid >> 6] = ss;
  __syncthreads();
  if (tid == 0) red[0] = sqrtf(red[0] + red[1] + red[2] + red[3]);
  __syncthreads();
  const float inv_norm = 1.0f / red[0];
  ushort* krow = kout + (size_t)h * KPAD;
  for (int m = tid; m < LFULL; m += 256) krow[8191 - m] = f2bf(kv[m] * inv_norm);
  if (tid < 128) krow[8192 + tid] = 0;
}

// ---------------------------------------------------------------------------
// Kernel 2: causal conv via block-Toeplitz 32x32x16 MFMA. Block = 1 h, 4
// waves (one per b). No barriers and NO asm fences in the main loop: the
// kbrev ring is register-staged (global->reg->ds_write, private per wave),
// so all waits are compiler-managed data deps and the scheduler can pipeline
// window builds across d-iterations into MFMA shadows.
// ---------------------------------------------------------------------------
__global__ __launch_bounds__(256, 2) void conv_mfma_kernel(
    const float* __restrict__ u, const ushort* __restrict__ kbrev,
    const float* __restrict__ Dp, ushort* __restrict__ g) {
  __shared__ __align__(16) ushort Us[4 * LFULL];  // 64 KB
  __shared__ __align__(16) ushort Ring[4][640];   // per-wave kbrev rings
  const int tid = threadIdx.x;
  const int h = blockIdx.x;
  const int w = tid >> 6;  // wave index == b
  const int lane = tid & 63;
  const int c32 = lane & 31;
  const int qh = lane >> 5;
  uint4* Us4 = (uint4*)Us;

  // ---- stage u: fp32 -> bf16, swizzled 16B chunks ----
  for (int cc = tid; cc < 4096; cc += 256) {
    const int row = cc >> 10, cI = cc & 1023;
    const float* up = u + (((size_t)(row * HDIM + h)) << 13) + (cI << 3);
    const float4 v0 = *(const float4*)up;
    const float4 v1 = *(const float4*)(up + 4);
    U16 pk;
    pk.e[0] = f2bf(v0.x); pk.e[1] = f2bf(v0.y);
    pk.e[2] = f2bf(v0.z); pk.e[3] = f2bf(v0.w);
    pk.e[4] = f2bf(v1.x); pk.e[5] = f2bf(v1.y);
    pk.e[6] = f2bf(v1.z); pk.e[7] = f2bf(v1.w);
    const int phys = (cI & ~7) | ((cI & 7) ^ ((cI >> 3) & 7));
    Us4[(row << 10) + phys] = pk.u;
  }

  // ---- ring prologue: chunks 64,63,62 staged via regs; 61 kept in kreg ----
  const ushort* kr = kbrev + (size_t)h * KPAD;
  ushort* ring = (ushort*)Ring[w];
  {
    const uint k64 = *(const uint*)(kr + 64 * 128 + 2 * lane);
    const uint k63 = *(const uint*)(kr + 63 * 128 + 2 * lane);
    const uint k62 = *(const uint*)(kr + 62 * 128 + 2 * lane);
    *(uint*)(ring + 0 * 128 + 2 * lane) = k64;  // slot 0 (64&3==0)
    *(uint*)(ring + 512 + 2 * lane) = k64;      // dup for wraparound reads
    *(uint*)(ring + 3 * 128 + 2 * lane) = k63;  // slot 63&3==3
    *(uint*)(ring + 2 * 128 + 2 * lane) = k62;  // slot 2
  }
  uint kreg = *(const uint*)(kr + 61 * 128 + 2 * lane);
  __syncthreads();

  f32x16 acc[4][2];
#pragma unroll
  for (int f = 0; f < 4; ++f)
#pragma unroll
    for (int rg = 0; rg < 2; ++rg)
#pragma unroll
      for (int q = 0; q < 16; ++q) acc[f][rg][q] = 0.0f;

  const uint shby = ((uint)((c32 & 1) ^ 1)) * 2u;  // byte shift for extract
  int Pb = 8191 - c32 + 8 * qh;  // kbrev index for m=0 at current d
  int dcnt = 61;                 // chunk currently held in kreg

  for (int d = 0; d < 128; ++d) {
    if ((d & 1) == 0) {
      // commit kreg's chunk to the ring; prefetch next into kreg.
      const int cw = dcnt < 0 ? 0 : dcnt;
      const int slot = (cw & 3) * 128;
      *(uint*)(ring + slot + 2 * lane) = kreg;
      *(uint*)(ring + ((slot == 0) ? 512 : slot) + 2 * lane) = kreg;
      const int cn = (dcnt - 1) < 0 ? 0 : (dcnt - 1);
      kreg = *(const uint*)(kr + cn * 128 + 2 * lane);
      dcnt--;
    }
    // build 6 A-windows: W[mm][lane][j] = k[64d + 16*(mm-3) + c32 - 8*qh - j]
    bf16x8 W[6];
#pragma unroll
    for (int mm = 0; mm < 6; ++mm) {
      const int P = Pb + 48 - 16 * mm;
      const int pos = (P & ~1) & 511;
      const ushort* rp = ring + pos;
      const uint dw0 = *(const uint*)(rp);
      const uint dw1 = *(const uint*)(rp + 2);
      const uint dw2 = *(const uint*)(rp + 4);
      const uint dw3 = *(const uint*)(rp + 6);
      const uint dw4 = *(const uint*)(rp + 8);
      U16 wv;
      wv.u.x = ALIGNB(dw1, dw0, shby);
      wv.u.y = ALIGNB(dw2, dw1, shby);
      wv.u.z = ALIGNB(dw3, dw2, shby);
      wv.u.w = ALIGNB(dw4, dw3, shby);
      W[mm] = wv.s;
    }
    const int dc = d >> 5, dl = d & 31;
#pragma unroll
    for (int f = 0; f < 4; ++f) {
      if (f >= dc) {
        const int j0 = f * 32 + c32 - d;
        const int jc = j0 < 0 ? 0 : j0;
        const int m8 = jc & 7;
        const uint4* ub = Us4 + (w << 10) + (jc << 3);
        uint4 B[4];
#pragma unroll
        for (int ks = 0; ks < 4; ++ks) B[ks] = ub[(2 * ks + qh) ^ m8];
        if (f == dc && dl != 0) {
          const bool kp = (c32 >= dl);
#pragma unroll
          for (int ks = 0; ks < 4; ++ks) {
            B[ks].x = kp ? B[ks].x : 0u;
            B[ks].y = kp ? B[ks].y : 0u;
            B[ks].z = kp ? B[ks].z : 0u;
            B[ks].w = kp ? B[ks].w : 0u;
          }
        }
#pragma unroll
        for (int rg = 0; rg < 2; ++rg) {
#pragma unroll
          for (int ks = 0; ks < 4; ++ks) {
            U16 bb;
            bb.u = B[ks];
            acc[f][rg] = __builtin_amdgcn_mfma_f32_32x32x16_bf16(
                W[2 * rg - ks + 3], bb.s, acc[f][rg], 0, 0, 0);
          }
        }
      }
    }
    Pb -= 64;
  }

  // ---- epilogue: += D*u, exact GELU, bf16 store ----
  const float Dh = Dp[h];
  ushort* gp = g + (((size_t)(w * HDIM + h)) << 13);
#pragma unroll
  for (int f = 0; f < 4; ++f) {
#pragma unroll
    for (int rg = 0; rg < 2; ++rg) {
      const int lbase = (f * 32 + c32) * 64 + rg * 32 + 4 * qh;
#pragma unroll
      for (int rq = 0; rq < 4; ++rq) {
        const int l = lbase + 8 * rq;
        const int cI = l >> 3;
        const int phys = (cI & ~7) | ((cI & 7) ^ ((cI >> 3) & 7));
        const uint2 uv =
            *(const uint2*)(Us + (w << 13) + (phys << 3) + 4 * qh);
        float uu[4];
        uu[0] = bf2f((ushort)(uv.x & 0xffff));
        uu[1] = bf2f((ushort)(uv.x >> 16));
        uu[2] = bf2f((ushort)(uv.y & 0xffff));
        uu[3] = bf2f((ushort)(uv.y >> 16));
        ushort o[4];
#pragma unroll
        for (int jj = 0; jj < 4; ++jj) {
          const float y = acc[f][rg][rq * 4 + jj] + Dh * uu[jj];
          const float ge = 0.5f * y * (1.0f + erff(y * 0.70710678118654752f));
          o[jj] = f2bf(ge);
        }
        uint2 op;
        op.x = (uint)o[0] | ((uint)o[1] << 16);
        op.y = (uint)o[2] | ((uint)o[3] << 16);
        *(uint2*)(gp + l) = op;
      }
    }
  }
}

// ---------------------------------------------------------------------------
// Kernel 3: transpose g[b][h][l] -> gt[b][l][h] (64x64 tiles, XOR-swizzled)
// ---------------------------------------------------------------------------
__global__ __launch_bounds__(256) void transpose_kernel(
    const ushort* __restrict__ g, ushort* __restrict__ gt) {
  __shared__ __align__(16) ushort Ts[64 * 64];
  const int l0 = blockIdx.x * 64, hh0 = blockIdx.y * 64, b = blockIdx.z;
  const int tid = threadIdx.x;
#pragma unroll
  for (int p = 0; p < 2; ++p) {
    const int hh = (tid >> 3) + 32 * p;
    const int c8 = tid & 7;
    const uint4 v = *(const uint4*)(g + (((size_t)(b * HDIM + hh0 + hh)) << 13)
                                    + l0 + c8 * 8);
    ((uint4*)Ts)[hh * 8 + (c8 ^ ((hh >> 3) & 7))] = v;
  }
  __syncthreads();
#pragma unroll
  for (int p = 0; p < 2; ++p) {
    const int lr = (tid >> 3) + 32 * p;
    const int o8 = tid & 7;
    U16 pk;
#pragma unroll
    for (int j = 0; j < 8; ++j) {
      const int hq = o8 * 8 + j;
      pk.e[j] = Ts[hq * 64 + (((lr >> 3) ^ o8) << 3) + (lr & 7)];
    }
    ((uint4*)(gt + ((size_t)b * LFULL + l0 + lr) * HDIM + hh0))[o8] = pk.u;
  }
}

// ---------------------------------------------------------------------------
// Kernel 4: W fp32 -> bf16
// ---------------------------------------------------------------------------
__global__ __launch_bounds__(256) void wcvt_kernel(const float* __restrict__ W,
                                                   ushort* __restrict__ Wb) {
  const int i = (blockIdx.x * 256 + threadIdx.x) * 8;
  const float4 v0 = *(const float4*)(W + i);
  const float4 v1 = *(const float4*)(W + i + 4);
  U16 pk;
  pk.e[0] = f2bf(v0.x); pk.e[1] = f2bf(v0.y);
  pk.e[2] = f2bf(v0.z); pk.e[3] = f2bf(v0.w);
  pk.e[4] = f2bf(v1.x); pk.e[5] = f2bf(v1.y);
  pk.e[6] = f2bf(v1.z); pk.e[7] = f2bf(v1.w);
  ((uint4*)Wb)[i >> 3] = pk.u;
}

// ---------------------------------------------------------------------------
// Kernel 5: out[b,o,l] = bo[o] + sum_h Wb[o,h]*gt[b,l,h]  (128x128 MFMA GEMM)
// ---------------------------------------------------------------------------
__global__ __launch_bounds__(256, 2) void outmm_kernel(
    const ushort* __restrict__ Wb, const ushort* __restrict__ gt,
    const float* __restrict__ bo, float* __restrict__ out) {
  __shared__ __align__(16) ushort As[128 * 32];
  __shared__ __align__(16) ushort Bs[128 * 32];
  const int tid = threadIdx.x;
  const int l0 = blockIdx.x * 128, o0 = blockIdx.y * 128, b = blockIdx.z;
  const int w = tid >> 6, lane = tid & 63;
  const int wm = w >> 1, wn = w & 1;
  const int col = lane & 15, q = lane >> 4;
  const int srow = lane >> 2, scol = (lane & 3) * 8;
  f32x4 acc[4][4];
#pragma unroll
  for (int m = 0; m < 4; ++m)
#pragma unroll
    for (int n = 0; n < 4; ++n) acc[m][n] = (f32x4){0.f, 0.f, 0.f, 0.f};
  const ushort* gb = gt + ((size_t)b * LFULL) * HDIM;
  for (int kt = 0; kt < 32; ++kt) {
    const int k0 = kt * 32;
    const int r0 = w * 32;
#pragma unroll
    for (int ii = 0; ii < 2; ++ii) {
      const int ra = r0 + ii * 16 + srow;
      gload16(Wb + (size_t)(o0 + ra) * HDIM + k0 + scol,
              As + (r0 + ii * 16) * 32);
      gload16(gb + (size_t)(l0 + ra) * HDIM + k0 + scol,
              Bs + (r0 + ii * 16) * 32);
    }
    __syncthreads();
    bf16x8 aa[4], bb[4];
#pragma unroll
    for (int m = 0; m < 4; ++m) {
      aa[m] = ((const bf16x8*)As)[(wm * 64 + m * 16 + col) * 4 + q];
      bb[m] = ((const bf16x8*)Bs)[(wn * 64 + m * 16 + col) * 4 + q];
    }
#pragma unroll
    for (int m = 0; m < 4; ++m)
#pragma unroll
      for (int n = 0; n < 4; ++n)
        acc[m][n] = __builtin_amdgcn_mfma_f32_16x16x32_bf16(aa[m], bb[n],
                                                            acc[m][n], 0, 0, 0);
    __syncthreads();
  }
#pragma unroll
  for (int m = 0; m < 4; ++m) {
    const int ob = o0 + wm * 64 + m * 16 + q * 4;
    const float4 bv = *(const float4*)(bo + ob);
    const float bva[4] = {bv.x, bv.y, bv.z, bv.w};
#pragma unroll
    for (int n = 0; n < 4; ++n) {
      const int l = l0 + wn * 64 + n * 16 + col;
      float* op = out + (((size_t)(b * HDIM + ob)) << 13) + l;
#pragma unroll
      for (int v = 0; v < 4; ++v) op[(size_t)v << 13] = acc[m][n][v] + bva[v];
    }
  }
}

// ---------------------------------------------------------------------------
extern "C" void kernel_launch(void* const* d_in, const int* in_sizes, int n_in,
                              void* d_out, int out_size, void* d_ws,
                              size_t ws_size, hipStream_t stream) {
  const float* u = (const float*)d_in[0];     // (4, 1024, 8192)
  const float* kern = (const float*)d_in[1];  // (8, 1, 1024, 64)
  const float* D = (const float*)d_in[2];     // (1, 1024)
  const float* W = (const float*)d_in[3];     // (1024, 1024)
  const float* bo = (const float*)d_in[4];    // (1024,)
  float* out = (float*)d_out;                 // (4, 1024, 8192)

  char* ws = (char*)d_ws;
  ushort* g = (ushort*)ws;                                 // [0, 64 MiB)
  ushort* gt = (ushort*)(ws + ((size_t)64 << 20));         // [64, 128 MiB)
  ushort* kbrev = (ushort*)(ws + ((size_t)128 << 20));     // [128, ~144.3 MiB)
  ushort* Wb = (ushort*)(ws + ((size_t)128 << 20));        // reuses kbrev region

  k_synth_kernel<<<HDIM, 256, 0, stream>>>(kern, kbrev);
  conv_mfma_kernel<<<HDIM, 256, 0, stream>>>(u, kbrev, D, g);
  // kbrev dead from here; Wb overlays it.
  wcvt_kernel<<<512, 256, 0, stream>>>(W, Wb);
  transpose_kernel<<<dim3(128, 16, 4), 256, 0, stream>>>(g, gt);
  outmm_kernel<<<dim3(64, 8, 4), 256, 0, stream>>>(Wb, gt, bo, out);
}